// Round 3
// baseline (206.059 us; speedup 1.0000x reference)
//
#include <hip/hip_runtime.h>

typedef __attribute__((ext_vector_type(8))) __bf16 bf16x8;
typedef __attribute__((ext_vector_type(2))) __bf16 bf16x2;
typedef __attribute__((ext_vector_type(8))) unsigned short u16x8;
typedef __attribute__((ext_vector_type(4))) float f32x4;
typedef __attribute__((ext_vector_type(16))) float f32x16;
typedef __attribute__((ext_vector_type(4))) unsigned int u32x4;
typedef unsigned short u16;
typedef unsigned int u32;

constexpr int Bb = 4, Ss = 2048, Ee = 1024, Hh = 16, HDd = 64;
constexpr int Mm = Bb * Ss;   // 8192
constexpr int N3 = 3 * Ee;    // 3072
constexpr float QSC = 0.18033688011112042f;  // 0.125 * log2(e)

__device__ __forceinline__ u16 f2bf(float f) {
  u32 u = __builtin_bit_cast(u32, f);
  u = (u + 0x7FFFu + ((u >> 16) & 1u)) >> 16;
  return (u16)u;
}
__device__ __forceinline__ u32 pk2(float a, float b) {
  bf16x2 t;
  t[0] = (__bf16)a;
  t[1] = (__bf16)b;
  return __builtin_bit_cast(u32, t);
}

__device__ __forceinline__ void gload_lds16(const void* g, void* l) {
  __builtin_amdgcn_global_load_lds(
      (__attribute__((address_space(1))) void*)g,
      (__attribute__((address_space(3))) void*)l, 16, 0, 0);
}

__device__ __forceinline__ f32x4 mfma16(bf16x8 a, bf16x8 b, f32x4 c) {
  return __builtin_amdgcn_mfma_f32_16x16x32_bf16(a, b, c, 0, 0, 0);
}
__device__ __forceinline__ f32x16 mfma32(bf16x8 a, bf16x8 b, f32x16 c) {
  return __builtin_amdgcn_mfma_f32_32x32x16_bf16(a, b, c, 0, 0, 0);
}

// ---------------- cast fp32 -> bf16 ----------------
__global__ void cast_x_kernel(const float* __restrict__ x, u16* __restrict__ xb, int n4) {
  int i = blockIdx.x * blockDim.x + threadIdx.x;
  int stride = gridDim.x * blockDim.x;
  for (; i < n4; i += stride) {
    float4 v = reinterpret_cast<const float4*>(x)[i];
    ushort4 o;
    o.x = f2bf(v.x); o.y = f2bf(v.y); o.z = f2bf(v.z); o.w = f2bf(v.w);
    reinterpret_cast<ushort4*>(xb)[i] = o;
  }
}

// ---------------- transpose-cast weight [K][N] fp32 -> [N][K] bf16 ----------------
__global__ void transpose_cast_kernel(const float* __restrict__ W, u16* __restrict__ Wt,
                                      int K, int N) {
  __shared__ float tile[32][33];
  int n0 = blockIdx.x * 32, k0 = blockIdx.y * 32;
  int tx = threadIdx.x & 31, ty = threadIdx.x >> 5;
#pragma unroll
  for (int i = 0; i < 4; ++i)
    tile[ty + i * 8][tx] = W[(size_t)(k0 + ty + i * 8) * N + n0 + tx];
  __syncthreads();
#pragma unroll
  for (int i = 0; i < 4; ++i)
    Wt[(size_t)(n0 + ty + i * 8) * K + k0 + tx] = f2bf(tile[tx][ty + i * 8]);
}

// ---------------- bf16 GEMM: C = A[M][K] * Bt[N][K]^T + bias ----------------
// QSCALE: scale Q columns ((n%192)<64) by QSC so attn softmax runs in exp2 units.
template <bool OUT_BF16, bool QSCALE>
__global__ __launch_bounds__(256) void gemm_kernel(
    const u16* __restrict__ A, const u16* __restrict__ Bt,
    const float* __restrict__ bias, void* __restrict__ Cout,
    int M, int N, int K) {
  __shared__ __attribute__((aligned(16))) u16 ldsA[128 * 32];
  __shared__ __attribute__((aligned(16))) u16 ldsB[128 * 32];
  int tid = threadIdx.x;
  int lane = tid & 63, w = tid >> 6;
  int wr = w >> 1, wc = w & 1;
  int m0 = blockIdx.y * 128, n0 = blockIdx.x * 128;
  const f32x4 fz = {0.f, 0.f, 0.f, 0.f};
  f32x4 acc[4][4];
#pragma unroll
  for (int mi = 0; mi < 4; ++mi)
#pragma unroll
    for (int nj = 0; nj < 4; ++nj) acc[mi][nj] = fz;

  int srow = tid >> 2;
  int scol = (tid & 3) * 8;
  const u16* aptr = A + (size_t)(m0 + srow) * K + scol;
  const u16* bptr = Bt + (size_t)(n0 + srow) * K + scol;
  u16* la = &ldsA[srow * 32 + scol];
  u16* lb = &ldsB[srow * 32 + scol];

  for (int k0 = 0; k0 < K; k0 += 32) {
    gload_lds16(aptr + k0, la);
    gload_lds16(aptr + k0 + (size_t)64 * K, la + 64 * 32);
    gload_lds16(bptr + k0, lb);
    gload_lds16(bptr + k0 + (size_t)64 * K, lb + 64 * 32);
    __syncthreads();
    bf16x8 af[4], bfr[4];
#pragma unroll
    for (int mi = 0; mi < 4; ++mi)
      af[mi] = *(const bf16x8*)&ldsA[(wr * 64 + mi * 16 + (lane & 15)) * 32 + (lane >> 4) * 8];
#pragma unroll
    for (int nj = 0; nj < 4; ++nj)
      bfr[nj] = *(const bf16x8*)&ldsB[(wc * 64 + nj * 16 + (lane & 15)) * 32 + (lane >> 4) * 8];
#pragma unroll
    for (int mi = 0; mi < 4; ++mi)
#pragma unroll
      for (int nj = 0; nj < 4; ++nj)
        acc[mi][nj] = mfma16(af[mi], bfr[nj], acc[mi][nj]);
    __syncthreads();
  }

#pragma unroll
  for (int mi = 0; mi < 4; ++mi) {
#pragma unroll
    for (int nj = 0; nj < 4; ++nj) {
      int n = n0 + wc * 64 + nj * 16 + (lane & 15);
      float bn = bias[n];
      float cs = (QSCALE && ((n % 192) < 64)) ? QSC : 1.0f;
#pragma unroll
      for (int r = 0; r < 4; ++r) {
        int m = m0 + wr * 64 + mi * 16 + (lane >> 4) * 4 + r;
        float v = (acc[mi][nj][r] + bn) * cs;
        if (OUT_BF16)
          ((u16*)Cout)[(size_t)m * N + n] = f2bf(v);
        else
          ((float*)Cout)[(size_t)m * N + n] = v;
      }
    }
  }
}

// ---------------- V transpose: qkv V-cols -> vt[bh][d=64][s=2048] ----------------
// Coalesced read (u16x8 per lane along d), coalesced write (lanes = consecutive s).
__global__ __launch_bounds__(256) void vtrans_kernel(const u16* __restrict__ qkv,
                                                     u16* __restrict__ vt) {
  int bh = blockIdx.x;
  int b = bh >> 4, h = bh & 15;
  int s0 = blockIdx.y * 64;
  int lane = threadIdx.x & 63, w = threadIdx.x >> 6;
  const u16* src = qkv + ((size_t)(b * Ss + s0 + lane)) * N3 + h * 192 + 128;
  u16* dst = vt + (size_t)bh * 64 * Ss + s0 + lane;
#pragma unroll
  for (int c = 0; c < 2; ++c) {
    int dc = w + c * 4;
    u16x8 vv = *(const u16x8*)(src + dc * 8);
#pragma unroll
    for (int j = 0; j < 8; ++j)
      dst[(size_t)(dc * 8 + j) * Ss] = vv[j];
  }
}

// ---------------- causal flash attention, swapped-operand 32x32 ----------------
// Double-buffered K/Vt staging via global_load_lds; softmax in exp2 units
// (scale pre-folded into Q by GEMM1); defer-max rescale; diag-only masking.
__global__ __launch_bounds__(256) void attn_kernel(const u16* __restrict__ qkv,
                                                   const u16* __restrict__ vt,
                                                   u16* __restrict__ aout) {
  __shared__ __attribute__((aligned(16))) u16 ldsK[2][4096];   // [kv][d] swizzled
  __shared__ __attribute__((aligned(16))) u16 ldsVt[2][4096];  // [d][kv] swizzled

  int bh = blockIdx.x;
  int qi = gridDim.y - 1 - blockIdx.y;  // big q-blocks first
  int b = bh >> 4, h = bh & 15;
  int tid = threadIdx.x, lane = tid & 63, w = tid >> 6;
  int hi = lane >> 5, ln31 = lane & 31;
  int q0 = qi * 128;
  int qrow = q0 + w * 32 + ln31;
  int qw_min = q0 + w * 32;
  int qw_max = qw_min + 31;

  const u16* base = qkv + (size_t)b * Ss * N3 + h * (3 * HDd);
  const u16* kbase = base + HDd;
  const u16* vbase = vt + (size_t)bh * 64 * Ss;

  // Q fragments (already scaled by 0.125*log2e)
  bf16x8 qf[4];
#pragma unroll
  for (int kc = 0; kc < 4; ++kc)
    qf[kc] = *(const bf16x8*)(base + (size_t)qrow * N3 + kc * 16 + hi * 8);

  f32x16 o[2];
#pragma unroll
  for (int dm = 0; dm < 2; ++dm)
#pragma unroll
    for (int e = 0; e < 16; ++e) o[dm][e] = 0.f;
  float mrun = -__builtin_inff(), lrun = 0.f;

  int rsub = lane >> 3;                 // 0..7 row-within-chunk
  int csw = ((lane & 7) ^ rsub) * 8;    // swizzled 16B slot

  int ntiles = 2 * qi + 2;

  // prologue: stage tile 0 into buf 0
#pragma unroll
  for (int c = 0; c < 2; ++c) {
    int ch = w * 2 + c;
    int r = ch * 8 + rsub;
    gload_lds16(kbase + (size_t)r * N3 + csw, &ldsK[0][ch * 512]);
    gload_lds16(vbase + (size_t)r * Ss + csw, &ldsVt[0][ch * 512]);
  }

  for (int t = 0; t < ntiles; ++t) {
    int kv0 = t * 64;
    int cur = t & 1;
    __syncthreads();  // stage(t) complete; prior readers of buf cur^1 done
    if (t + 1 < ntiles) {
      int kv1 = kv0 + 64;
#pragma unroll
      for (int c = 0; c < 2; ++c) {
        int ch = w * 2 + c;
        int r = ch * 8 + rsub;
        gload_lds16(kbase + (size_t)(kv1 + r) * N3 + csw, &ldsK[cur ^ 1][ch * 512]);
        gload_lds16(vbase + (size_t)r * Ss + kv1 + csw, &ldsVt[cur ^ 1][ch * 512]);
      }
    }

    if (kv0 <= qw_max) {
      // ---- QK^T swapped: sc[mt] = S^T[32mt+kv', q] (exp2 units) ----
      f32x16 sc[2];
#pragma unroll
      for (int mt = 0; mt < 2; ++mt)
#pragma unroll
        for (int e = 0; e < 16; ++e) sc[mt][e] = 0.f;
      __builtin_amdgcn_s_setprio(1);
#pragma unroll
      for (int mt = 0; mt < 2; ++mt) {
        int row = 32 * mt + ln31;
#pragma unroll
        for (int kc = 0; kc < 4; ++kc) {
          bf16x8 kf = *(const bf16x8*)&ldsK[cur][row * 64 + ((kc * 16 + hi * 8) ^ ((row & 7) << 3))];
          sc[mt] = mfma32(kf, qf[kc], sc[mt]);
        }
      }
      __builtin_amdgcn_s_setprio(0);

      // ---- online softmax (lane owns q-row; exp2 domain) ----
      bool diag = (kv0 + 63 > qw_min);
      float mx = -__builtin_inff();
      if (diag) {
#pragma unroll
        for (int mt = 0; mt < 2; ++mt)
#pragma unroll
          for (int r = 0; r < 16; ++r) {
            int kvg = kv0 + 32 * mt + (r & 3) + 8 * (r >> 2) + 4 * hi;
            float s = (kvg > qrow) ? -__builtin_inff() : sc[mt][r];
            sc[mt][r] = s;
            mx = fmaxf(mx, s);
          }
      } else {
#pragma unroll
        for (int mt = 0; mt < 2; ++mt)
#pragma unroll
          for (int r = 0; r < 16; ++r) mx = fmaxf(mx, sc[mt][r]);
      }
      mx = fmaxf(mx, __shfl_xor(mx, 32));
      if (!__all(mx <= mrun + 8.0f)) {  // defer-max (T13)
        float mnew = fmaxf(mrun, mx);
        float corr = __builtin_exp2f(mrun - mnew);
        mrun = mnew;
        lrun *= corr;
#pragma unroll
        for (int dm = 0; dm < 2; ++dm)
#pragma unroll
          for (int e = 0; e < 16; ++e) o[dm][e] *= corr;
      }
      float sum = 0.f;
#pragma unroll
      for (int mt = 0; mt < 2; ++mt)
#pragma unroll
        for (int r = 0; r < 16; ++r) {
          float e = __builtin_exp2f(sc[mt][r] - mrun);
          sc[mt][r] = e;
          sum += e;
        }
      sum += __shfl_xor(sum, 32);
      lrun += sum;

      // ---- P pack + xor-32 exchange -> B-frags; PV ----
#pragma unroll
      for (int kw = 0; kw < 4; ++kw) {
        int mt = kw >> 1, k8 = (kw & 1) * 8;
        u32 a0 = pk2(sc[mt][k8 + 0], sc[mt][k8 + 1]);
        u32 a1 = pk2(sc[mt][k8 + 2], sc[mt][k8 + 3]);
        u32 b0 = pk2(sc[mt][k8 + 4], sc[mt][k8 + 5]);
        u32 b1 = pk2(sc[mt][k8 + 6], sc[mt][k8 + 7]);
        u32 s0 = hi ? a0 : b0;
        u32 s1 = hi ? a1 : b1;
        u32 r0 = (u32)__shfl_xor((int)s0, 32);
        u32 r1 = (u32)__shfl_xor((int)s1, 32);
        u32x4 fw;
        fw.x = hi ? r0 : a0;
        fw.y = hi ? r1 : a1;
        fw.z = hi ? b0 : r0;
        fw.w = hi ? b1 : r1;
        bf16x8 pf = __builtin_bit_cast(bf16x8, fw);
        __builtin_amdgcn_s_setprio(1);
#pragma unroll
        for (int dm = 0; dm < 2; ++dm) {
          int d = 32 * dm + ln31;
          bf16x8 vf = *(const bf16x8*)&ldsVt[cur][d * 64 + ((kw * 16 + hi * 8) ^ ((d & 7) << 3))];
          o[dm] = mfma32(vf, pf, o[dm]);  // O^T[d][q]
        }
        __builtin_amdgcn_s_setprio(0);
      }
    }
  }

  // ---- epilogue ----
  float inv = 1.f / lrun;
  u16* orow = aout + (size_t)(b * Ss + qrow) * Ee + h * HDd;
#pragma unroll
  for (int dm = 0; dm < 2; ++dm)
#pragma unroll
    for (int g = 0; g < 4; ++g) {
      ushort4 st;
      st.x = f2bf(o[dm][4 * g + 0] * inv);
      st.y = f2bf(o[dm][4 * g + 1] * inv);
      st.z = f2bf(o[dm][4 * g + 2] * inv);
      st.w = f2bf(o[dm][4 * g + 3] * inv);
      *(ushort4*)(orow + 32 * dm + 8 * g + 4 * hi) = st;
    }
}

// ---------------- launch ----------------
extern "C" void kernel_launch(void* const* d_in, const int* in_sizes, int n_in,
                              void* d_out, int out_size, void* d_ws, size_t ws_size,
                              hipStream_t stream) {
  const float* hs        = (const float*)d_in[0];
  const float* c_attn_w  = (const float*)d_in[1];
  const float* c_attn_b  = (const float*)d_in[2];
  const float* c_proj_w  = (const float*)d_in[3];
  const float* c_proj_b  = (const float*)d_in[4];
  float* out = (float*)d_out;

  char* ws = (char*)d_ws;
  size_t off = 0;
  u16* xb     = (u16*)(ws + off); off += (size_t)Mm * Ee * 2;
  u16* wqkvt  = (u16*)(ws + off); off += (size_t)N3 * Ee * 2;
  u16* wprojt = (u16*)(ws + off); off += (size_t)Ee * Ee * 2;
  u16* qkv    = (u16*)(ws + off); off += (size_t)Mm * N3 * 2;
  u16* aoutb  = (u16*)(ws + off); off += (size_t)Mm * Ee * 2;
  u16* vtb    = xb;  // xb is dead after GEMM1; vtrans runs after GEMM1 on same stream
  if (ws_size < off) return;

  cast_x_kernel<<<2048, 256, 0, stream>>>(hs, xb, Mm * Ee / 4);
  transpose_cast_kernel<<<dim3(N3 / 32, Ee / 32), 256, 0, stream>>>(c_attn_w, wqkvt, Ee, N3);
  transpose_cast_kernel<<<dim3(Ee / 32, Ee / 32), 256, 0, stream>>>(c_proj_w, wprojt, Ee, Ee);
  gemm_kernel<true, true><<<dim3(N3 / 128, Mm / 128), 256, 0, stream>>>(
      xb, wqkvt, c_attn_b, qkv, Mm, N3, Ee);
  vtrans_kernel<<<dim3(Bb * Hh, Ss / 64), 256, 0, stream>>>(qkv, vtb);
  attn_kernel<<<dim3(Bb * Hh, Ss / 128), 256, 0, stream>>>(qkv, vtb, aoutb);
  gemm_kernel<false, false><<<dim3(Ee / 128, Mm / 128), 256, 0, stream>>>(
      aoutb, wprojt, c_proj_b, out, Mm, Ee, Ee);
}